// Round 11
// baseline (420.293 us; speedup 1.0000x reference)
//
#include <hip/hip_runtime.h>
#include <math.h>

#define NN 100000
#define NE 1600000
#define NB 391     // ceil(NN/256)
#define PART 12500 // NN/8 nodes per XCD partition

typedef __attribute__((ext_vector_type(8))) short bf16x8;
typedef __attribute__((ext_vector_type(4))) float f32x4;

__device__ inline unsigned short f2bf(float f) {
  unsigned int u = __float_as_uint(f);
  u = u + 0x7fffu + ((u >> 16) & 1u);
  return (unsigned short)(u >> 16);
}
// packed dword (2 bf16) -> 2 floats
__device__ inline void unpk(unsigned int w, float& a, float& b) {
  a = __uint_as_float(w << 16);
  b = __uint_as_float(w & 0xffff0000u);
}

// ---------------- init: zero deg + weight prep (merged) ----------------
// Bp frag idx within matrix m: ((f*4+t)*64+lane)*8+u <-> n=f*16+(lane&15), k=t*32+(lane>>4)*8+u
// m=0: W1, m=1: W2, m=2: Wm1 rows 0..127, m=3: Wm1 rows 128..255
__global__ __launch_bounds__(256) void k_init(int* __restrict__ deg,
                                              const float* __restrict__ W1, const float* __restrict__ W2,
                                              const float* __restrict__ Wm1, unsigned short* __restrict__ Bp) {
  int gid = blockIdx.x * 256 + threadIdx.x;
  if (gid < NN) deg[gid] = 0;
  if (gid < 65536) {
    int idx = gid & 16383;
    int m = gid >> 14;
    int u = idx & 7;
    int lane = (idx >> 3) & 63;
    int ft = idx >> 9;
    int t = ft & 3, f = ft >> 2;
    int n = f * 16 + (lane & 15);
    int k = t * 32 + (lane >> 4) * 8 + u;
    const float* Wsrc = (m == 0) ? W1 : (m == 1) ? W2 : Wm1;
    int krow = (m == 3) ? (k + 128) : k;
    Bp[gid] = f2bf(Wsrc[(size_t)krow * 128 + n]);
  }
}

// XCD-partitioned histogram
__global__ __launch_bounds__(256) void k_hist(const int* __restrict__ dst, int* __restrict__ deg) {
  int b = blockIdx.x;
  int xcd = b & 7;
  int e = (b >> 3) * 256 + threadIdx.x;
  int d = dst[e];
  if ((unsigned)(d - xcd * PART) < (unsigned)PART) atomicAdd(&deg[d], 1);
}

__global__ __launch_bounds__(256) void k_scan1(const int* __restrict__ deg, int* __restrict__ tmp,
                                               int* __restrict__ bsum) {
  __shared__ int wsum[4];
  int i = blockIdx.x * 256 + threadIdx.x;
  int v = (i < NN) ? deg[i] : 0;
  int x = v;
#pragma unroll
  for (int d = 1; d < 64; d <<= 1) {
    int y = __shfl_up(x, d);
    if ((threadIdx.x & 63) >= d) x += y;
  }
  if ((threadIdx.x & 63) == 63) wsum[threadIdx.x >> 6] = x;
  __syncthreads();
  int add = 0;
  for (int w = 0; w < (threadIdx.x >> 6); ++w) add += wsum[w];
  int incl = x + add;
  if (i < NN) tmp[i] = incl - v;
  if (threadIdx.x == 255) bsum[blockIdx.x] = incl;
}

__global__ void k_scan2(const int* __restrict__ bsum, int* __restrict__ boff) {
  int lane = threadIdx.x;  // 64 threads
  int run = 0;
  for (int b0 = 0; b0 < NB; b0 += 64) {
    int i = b0 + lane;
    int v = (i < NB) ? bsum[i] : 0;
    int x = v;
#pragma unroll
    for (int d = 1; d < 64; d <<= 1) {
      int y = __shfl_up(x, d);
      if (lane >= d) x += y;
    }
    if (i < NB) boff[i] = run + x - v;
    run += __shfl(x, 63);
  }
}

__global__ __launch_bounds__(256) void k_scan3(const int* __restrict__ deg, int* __restrict__ tmp,
                                               const int* __restrict__ boff, int* __restrict__ rs,
                                               float* __restrict__ dinv) {
  int i = blockIdx.x * 256 + threadIdx.x;
  if (i < NN) {
    int v = tmp[i] + boff[blockIdx.x];
    rs[i] = v;
    tmp[i] = v;  // atomic cursor for k_fill
    dinv[i] = rsqrtf((float)(deg[i] + 1));
  }
  if (i == 0) rs[NN] = NE;
}

// XCD-partitioned fill. packed: lo = src | (d<<17) ; hi = (d>>15) | (eid<<2)
__global__ __launch_bounds__(256) void k_fill(const int* __restrict__ src, const int* __restrict__ dst,
                                              int* __restrict__ cursor, uint2* __restrict__ sde) {
  int b = blockIdx.x;
  int xcd = b & 7;
  int e = (b >> 3) * 256 + threadIdx.x;
  int d = dst[e];
  int s = src[e];
  if ((unsigned)(d - xcd * PART) < (unsigned)PART) {
    int p = atomicAdd(&cursor[d], 1);
    unsigned int lo = (unsigned int)s | ((unsigned int)d << 17);
    unsigned int hi = ((unsigned int)d >> 15) | ((unsigned int)e << 2);
    sde[p] = make_uint2(lo, hi);
  }
}

// ---------------- MFMA GEMM, fp32 A (layer 1: T1' = dinv * (x @ W1)) ----------------
__global__ __launch_bounds__(256) void k_gemm_mfma_f32(const float* __restrict__ A,
                                                       const unsigned short* __restrict__ Bp,
                                                       unsigned short* __restrict__ Y,
                                                       const float* __restrict__ scale, int nrows) {
  __shared__ unsigned short BL[16384];
  {
    const uint4* gp = (const uint4*)Bp;
    uint4* sp = (uint4*)BL;
#pragma unroll
    for (int i = 0; i < 8; ++i) sp[threadIdx.x + i * 256] = gp[threadIdx.x + i * 256];
  }
  __syncthreads();

  const int w = threadIdx.x >> 6, lane = threadIdx.x & 63;
  const int r = lane & 15, g = lane >> 4;
  const int rowbase = blockIdx.x * 64 + w * 16;
  const int arow = rowbase + r;

  bf16x8 av[4];
  if (arow < nrows) {
#pragma unroll
    for (int t = 0; t < 4; ++t) {
      float4 a0 = *(const float4*)(A + (size_t)arow * 128 + g * 8 + t * 32);
      float4 a1 = *(const float4*)(A + (size_t)arow * 128 + g * 8 + t * 32 + 4);
      bf16x8 pk;
      pk[0] = (short)f2bf(a0.x); pk[1] = (short)f2bf(a0.y);
      pk[2] = (short)f2bf(a0.z); pk[3] = (short)f2bf(a0.w);
      pk[4] = (short)f2bf(a1.x); pk[5] = (short)f2bf(a1.y);
      pk[6] = (short)f2bf(a1.z); pk[7] = (short)f2bf(a1.w);
      av[t] = pk;
    }
  } else {
#pragma unroll
    for (int t = 0; t < 4; ++t) av[t] = (bf16x8){0, 0, 0, 0, 0, 0, 0, 0};
  }

  f32x4 acc[8];
#pragma unroll
  for (int f = 0; f < 8; ++f) acc[f] = (f32x4){0.f, 0.f, 0.f, 0.f};

#pragma unroll
  for (int f = 0; f < 8; ++f)
#pragma unroll
    for (int t = 0; t < 4; ++t) {
      bf16x8 bv = *(const bf16x8*)(&BL[(((f << 2) | t) << 9) | (lane << 3)]);
      acc[f] = __builtin_amdgcn_mfma_f32_16x16x32_bf16(av[t], bv, acc[f], 0, 0, 0);
    }

#pragma unroll
  for (int j = 0; j < 4; ++j) {
    int row = rowbase + g * 4 + j;
    if (row < nrows) {
      float sc = scale[row];
#pragma unroll
      for (int f = 0; f < 8; ++f) Y[(size_t)row * 128 + f * 16 + r] = f2bf(acc[f][j] * sc);
    }
  }
}

// ---------------- FUSED: layer-1 aggregate + layer-2 GEMM ----------------
// Block (512 thr, 8 waves) owns 64 nodes: gather h1 rows into LDS (bf16, relu'd),
// then MFMA vs W2 frags -> T2' = dinv * (h1 @ W2).
__global__ __launch_bounds__(512) void k_aggemm(const unsigned short* __restrict__ T,
                                                const int* __restrict__ rs, const uint2* __restrict__ sde,
                                                const float* __restrict__ dinv, const float* __restrict__ bias,
                                                const unsigned short* __restrict__ Bp,
                                                unsigned short* __restrict__ Y) {
  __shared__ unsigned short BL[16384];
  __shared__ unsigned short HS[64][136];  // +8 pad: GEMM A-reads 2-way only
  {
    const uint4* gp = (const uint4*)Bp;
    uint4* sp = (uint4*)BL;
#pragma unroll
    for (int i = 0; i < 4; ++i) sp[threadIdx.x + i * 512] = gp[threadIdx.x + i * 512];
  }

  const int wv = threadIdx.x >> 6, lane = threadIdx.x & 63;
  const int q = lane >> 4, r = lane & 15;
  const int nbase = blockIdx.x * 64;

  // ---- gather phase: wave wv aggregates nodes nbase+wv*8 .. +7 ----
  for (int k = 0; k < 8; ++k) {
    int nl = wv * 8 + k;
    int node = nbase + nl;
    if (node < NN) {
      int beg = rs[node], end = rs[node + 1];
      float acc[8];
#pragma unroll
      for (int i = 0; i < 8; ++i) acc[i] = 0.f;
      for (int j0 = beg; j0 < end; j0 += 64) {
        int sl = (j0 + lane < end) ? (int)(sde[j0 + lane].x & 0x1FFFFu) : 0;
        int n = end - j0;
        if (n > 64) n = 64;
#pragma unroll 4
        for (int c = 0; c * 4 < n; ++c) {
          int idx = (c << 2) | q;
          int s = __shfl(sl, idx);
          if (idx < n) {
            uint4 hv = *(const uint4*)(T + (size_t)s * 128 + r * 8);
            float f0, f1, f2, f3, f4, f5, f6, f7;
            unpk(hv.x, f0, f1); unpk(hv.y, f2, f3);
            unpk(hv.z, f4, f5); unpk(hv.w, f6, f7);
            acc[0] += f0; acc[1] += f1; acc[2] += f2; acc[3] += f3;
            acc[4] += f4; acc[5] += f5; acc[6] += f6; acc[7] += f7;
          }
        }
      }
#pragma unroll
      for (int i = 0; i < 8; ++i) {
        acc[i] += __shfl_xor(acc[i], 16);
        acc[i] += __shfl_xor(acc[i], 32);
      }
      if (q == 0) {
        uint4 sv = *(const uint4*)(T + (size_t)node * 128 + r * 8);
        float s0, s1, s2, s3, s4, s5, s6, s7;
        unpk(sv.x, s0, s1); unpk(sv.y, s2, s3);
        unpk(sv.z, s4, s5); unpk(sv.w, s6, s7);
        float4 ba = *(const float4*)(bias + r * 8);
        float4 bb = *(const float4*)(bias + r * 8 + 4);
        float dn = dinv[node];
        float o0 = fmaxf(fmaf(dn, acc[0] + s0, ba.x), 0.f);
        float o1 = fmaxf(fmaf(dn, acc[1] + s1, ba.y), 0.f);
        float o2 = fmaxf(fmaf(dn, acc[2] + s2, ba.z), 0.f);
        float o3 = fmaxf(fmaf(dn, acc[3] + s3, ba.w), 0.f);
        float o4 = fmaxf(fmaf(dn, acc[4] + s4, bb.x), 0.f);
        float o5 = fmaxf(fmaf(dn, acc[5] + s5, bb.y), 0.f);
        float o6 = fmaxf(fmaf(dn, acc[6] + s6, bb.z), 0.f);
        float o7 = fmaxf(fmaf(dn, acc[7] + s7, bb.w), 0.f);
        uint4 pv;
        pv.x = (unsigned int)f2bf(o0) | ((unsigned int)f2bf(o1) << 16);
        pv.y = (unsigned int)f2bf(o2) | ((unsigned int)f2bf(o3) << 16);
        pv.z = (unsigned int)f2bf(o4) | ((unsigned int)f2bf(o5) << 16);
        pv.w = (unsigned int)f2bf(o6) | ((unsigned int)f2bf(o7) << 16);
        *(uint4*)(&HS[nl][r * 8]) = pv;
      }
    } else if (q == 0) {
      uint4 z = make_uint4(0u, 0u, 0u, 0u);
      *(uint4*)(&HS[nl][r * 8]) = z;
    }
  }
  __syncthreads();

  // ---- GEMM phase: wave wv -> rows (wv&3)*16..+15, cols (wv>>2)*64..+63 ----
  const int rows16 = (wv & 3) << 4;
  const int fh = wv >> 2;
  bf16x8 av[4];
#pragma unroll
  for (int t = 0; t < 4; ++t) av[t] = *(const bf16x8*)(&HS[rows16 + r][q * 8 + t * 32]);

  f32x4 acc4[4];
#pragma unroll
  for (int f = 0; f < 4; ++f) acc4[f] = (f32x4){0.f, 0.f, 0.f, 0.f};
#pragma unroll
  for (int f = 0; f < 4; ++f) {
    int fg = fh * 4 + f;
#pragma unroll
    for (int t = 0; t < 4; ++t) {
      bf16x8 bv = *(const bf16x8*)(&BL[(((fg << 2) | t) << 9) | (lane << 3)]);
      acc4[f] = __builtin_amdgcn_mfma_f32_16x16x32_bf16(av[t], bv, acc4[f], 0, 0, 0);
    }
  }
#pragma unroll
  for (int j = 0; j < 4; ++j) {
    int row = nbase + rows16 + q * 4 + j;
    if (row < NN) {
      float sc = dinv[row];
#pragma unroll
      for (int f = 0; f < 4; ++f)
        Y[(size_t)row * 128 + (fh * 4 + f) * 16 + r] = f2bf(acc4[f][j] * sc);
    }
  }
}

// ---------------- dual MFMA GEMM: U = A@Wm1t, V = A@Wm1b ----------------
__global__ __launch_bounds__(512) void k_gemm_dual(const unsigned short* __restrict__ A,
                                                   const unsigned short* __restrict__ Bp2,
                                                   unsigned short* __restrict__ U,
                                                   unsigned short* __restrict__ V, int nrows) {
  __shared__ unsigned short BL[32768];
  {
    const uint4* gp = (const uint4*)Bp2;
    uint4* sp = (uint4*)BL;
#pragma unroll
    for (int i = 0; i < 8; ++i) sp[threadIdx.x + i * 512] = gp[threadIdx.x + i * 512];
  }
  __syncthreads();

  const int w = threadIdx.x >> 6, lane = threadIdx.x & 63;
  const int r = lane & 15, g = lane >> 4;
  const int rowbase = blockIdx.x * 128 + w * 16;
  const int arow = rowbase + r;

  bf16x8 av[4];
  if (arow < nrows) {
#pragma unroll
    for (int t = 0; t < 4; ++t) av[t] = *(const bf16x8*)(A + (size_t)arow * 128 + g * 8 + t * 32);
  } else {
#pragma unroll
    for (int t = 0; t < 4; ++t) av[t] = (bf16x8){0, 0, 0, 0, 0, 0, 0, 0};
  }

  f32x4 accU[8], accV[8];
#pragma unroll
  for (int f = 0; f < 8; ++f) {
    accU[f] = (f32x4){0.f, 0.f, 0.f, 0.f};
    accV[f] = (f32x4){0.f, 0.f, 0.f, 0.f};
  }

#pragma unroll
  for (int f = 0; f < 8; ++f)
#pragma unroll
    for (int t = 0; t < 4; ++t) {
      bf16x8 bu = *(const bf16x8*)(&BL[(((f << 2) | t) << 9) | (lane << 3)]);
      bf16x8 bv = *(const bf16x8*)(&BL[16384 + ((((f << 2) | t) << 9) | (lane << 3))]);
      accU[f] = __builtin_amdgcn_mfma_f32_16x16x32_bf16(av[t], bu, accU[f], 0, 0, 0);
      accV[f] = __builtin_amdgcn_mfma_f32_16x16x32_bf16(av[t], bv, accV[f], 0, 0, 0);
    }

#pragma unroll
  for (int j = 0; j < 4; ++j) {
    int row = rowbase + g * 4 + j;
    if (row < nrows) {
#pragma unroll
      for (int f = 0; f < 8; ++f) {
        U[(size_t)row * 128 + f * 16 + r] = f2bf(accU[f][j]);
        V[(size_t)row * 128 + f * 16 + r] = f2bf(accV[f][j]);
      }
    }
  }
}

// ---------------- aggregate (layer 2), quarter-wave gather ----------------
__global__ __launch_bounds__(256) void k_agg(const unsigned short* __restrict__ T,
                                             const int* __restrict__ rs, const uint2* __restrict__ sde,
                                             const float* __restrict__ dinv, const float* __restrict__ bias,
                                             unsigned short* __restrict__ outB) {
  int node = blockIdx.x * 4 + (threadIdx.x >> 6);
  if (node >= NN) return;
  int lane = threadIdx.x & 63;
  int q = lane >> 4, r = lane & 15;
  int beg = rs[node], end = rs[node + 1];
  float dn = dinv[node];

  float acc[8];
#pragma unroll
  for (int i = 0; i < 8; ++i) acc[i] = 0.f;

  for (int j0 = beg; j0 < end; j0 += 64) {
    int sl = (j0 + lane < end) ? (int)(sde[j0 + lane].x & 0x1FFFFu) : 0;
    int n = end - j0;
    if (n > 64) n = 64;
#pragma unroll 4
    for (int c = 0; c * 4 < n; ++c) {
      int idx = (c << 2) | q;
      int s = __shfl(sl, idx);
      if (idx < n) {
        uint4 hv = *(const uint4*)(T + (size_t)s * 128 + r * 8);
        float f0, f1, f2, f3, f4, f5, f6, f7;
        unpk(hv.x, f0, f1); unpk(hv.y, f2, f3);
        unpk(hv.z, f4, f5); unpk(hv.w, f6, f7);
        acc[0] += f0; acc[1] += f1; acc[2] += f2; acc[3] += f3;
        acc[4] += f4; acc[5] += f5; acc[6] += f6; acc[7] += f7;
      }
    }
  }

#pragma unroll
  for (int i = 0; i < 8; ++i) {
    acc[i] += __shfl_xor(acc[i], 16);
    acc[i] += __shfl_xor(acc[i], 32);
  }

  uint4 sv = *(const uint4*)(T + (size_t)node * 128 + r * 8);
  float s0, s1, s2, s3, s4, s5, s6, s7;
  unpk(sv.x, s0, s1); unpk(sv.y, s2, s3);
  unpk(sv.z, s4, s5); unpk(sv.w, s6, s7);
  float4 ba = *(const float4*)(bias + r * 8);
  float4 bb = *(const float4*)(bias + r * 8 + 4);
  float o0 = fmaxf(fmaf(dn, acc[0] + s0, ba.x), 0.f);
  float o1 = fmaxf(fmaf(dn, acc[1] + s1, ba.y), 0.f);
  float o2 = fmaxf(fmaf(dn, acc[2] + s2, ba.z), 0.f);
  float o3 = fmaxf(fmaf(dn, acc[3] + s3, ba.w), 0.f);
  float o4 = fmaxf(fmaf(dn, acc[4] + s4, bb.x), 0.f);
  float o5 = fmaxf(fmaf(dn, acc[5] + s5, bb.y), 0.f);
  float o6 = fmaxf(fmaf(dn, acc[6] + s6, bb.z), 0.f);
  float o7 = fmaxf(fmaf(dn, acc[7] + s7, bb.w), 0.f);
  if (q == 0) {
    uint4 pv;
    pv.x = (unsigned int)f2bf(o0) | ((unsigned int)f2bf(o1) << 16);
    pv.y = (unsigned int)f2bf(o2) | ((unsigned int)f2bf(o3) << 16);
    pv.z = (unsigned int)f2bf(o4) | ((unsigned int)f2bf(o5) << 16);
    pv.w = (unsigned int)f2bf(o6) | ((unsigned int)f2bf(o7) << 16);
    *(uint4*)(outB + (size_t)node * 128 + r * 8) = pv;
  }
}

// ---------------- edge epilogue, XCD-pinned to dst partitions ----------------
// class c = blockIdx&7 covers batches [rs[c*PART]>>6, (rs[(c+1)*PART]+63)>>6) ->
// v-row reads confined to one partition slice (L2-resident per XCD).
// Boundary batches may run in two classes: identical results, benign.
__global__ __launch_bounds__(256) void k_edge(const unsigned short* __restrict__ u,
                                              const unsigned short* __restrict__ v,
                                              const uint2* __restrict__ sde, const int* __restrict__ rs,
                                              const float* __restrict__ bm1, const float* __restrict__ Wm2,
                                              const float* __restrict__ bm2, float* __restrict__ out) {
  __shared__ float red[4][16 * 65];
  const int w = threadIdx.x >> 6;
  const int lane = threadIdx.x & 63;
  const int q = lane >> 4, r = lane & 15;
  float* __restrict__ myred = &red[w][0];

  const int cls = blockIdx.x & 7;
  const int bi = blockIdx.x >> 3;  // 0..799
  const int lo = rs[cls * PART] >> 6;
  const int hi = (rs[(cls + 1) * PART] + 63) >> 6;  // rs[NN]=NE -> 25000 for cls=7
  const int bat = lo + bi * 4 + w;
  const bool active = bat < hi;

  float bmv[8], w2[8];
  {
    float4 a = *(const float4*)(bm1 + r * 8);
    float4 b = *(const float4*)(bm1 + r * 8 + 4);
    bmv[0] = a.x; bmv[1] = a.y; bmv[2] = a.z; bmv[3] = a.w;
    bmv[4] = b.x; bmv[5] = b.y; bmv[6] = b.z; bmv[7] = b.w;
    float4 c = *(const float4*)(Wm2 + r * 8);
    float4 d = *(const float4*)(Wm2 + r * 8 + 4);
    w2[0] = c.x; w2[1] = c.y; w2[2] = c.z; w2[3] = c.w;
    w2[4] = d.x; w2[5] = d.y; w2[6] = d.z; w2[7] = d.w;
  }
  const float b2 = bm2[0];

  uint2 ev = make_uint2(0u, 0u);
  if (active) ev = sde[bat * 64 + lane];
  const int sl = (int)(ev.x & 0x1FFFFu);
  const int dl = (int)((ev.x >> 17) | ((ev.y & 3u) << 15));

  if (active) {
    int cur = -1;
    float vb[8];
#pragma unroll
    for (int i = 0; i < 8; ++i) vb[i] = 0.f;

#pragma unroll 4
    for (int c = 0; c < 16; ++c) {
      int idx = (c << 2) | q;
      int s = __shfl(sl, idx);
      int d = __shfl(dl, idx);
      uint4 uu = *(const uint4*)(u + (size_t)s * 128 + r * 8);
      if (d != cur) {
        uint4 vv = *(const uint4*)(v + (size_t)d * 128 + r * 8);
        float g0, g1, g2, g3, g4, g5, g6, g7;
        unpk(vv.x, g0, g1); unpk(vv.y, g2, g3);
        unpk(vv.z, g4, g5); unpk(vv.w, g6, g7);
        vb[0] = g0 + bmv[0]; vb[1] = g1 + bmv[1];
        vb[2] = g2 + bmv[2]; vb[3] = g3 + bmv[3];
        vb[4] = g4 + bmv[4]; vb[5] = g5 + bmv[5];
        vb[6] = g6 + bmv[6]; vb[7] = g7 + bmv[7];
        cur = d;
      }
      float f0, f1, f2, f3, f4, f5, f6, f7;
      unpk(uu.x, f0, f1); unpk(uu.y, f2, f3);
      unpk(uu.z, f4, f5); unpk(uu.w, f6, f7);
      float p = 0.f;
      p = fmaf(fmaxf(f0 + vb[0], 0.f), w2[0], p);
      p = fmaf(fmaxf(f1 + vb[1], 0.f), w2[1], p);
      p = fmaf(fmaxf(f2 + vb[2], 0.f), w2[2], p);
      p = fmaf(fmaxf(f3 + vb[3], 0.f), w2[3], p);
      p = fmaf(fmaxf(f4 + vb[4], 0.f), w2[4], p);
      p = fmaf(fmaxf(f5 + vb[5], 0.f), w2[5], p);
      p = fmaf(fmaxf(f6 + vb[6], 0.f), w2[6], p);
      p = fmaf(fmaxf(f7 + vb[7], 0.f), w2[7], p);
      myred[c * 65 + q * 16 + r] = p;
    }
  }
  __syncthreads();

  if (active) {
    const float* row = &myred[(lane >> 2) * 65 + (lane & 3) * 16];
    float s0 = 0.f, s1 = 0.f;
#pragma unroll
    for (int k = 0; k < 16; k += 2) {
      s0 += row[k];
      s1 += row[k + 1];
    }
    float logit = s0 + s1 + b2;
    int eid = (int)(ev.y >> 2);
    out[eid] = 1.f / (1.f + __expf(-logit));
  }
}

// ---------------- launch ----------------
extern "C" void kernel_launch(void* const* d_in, const int* in_sizes, int n_in,
                              void* d_out, int out_size, void* d_ws, size_t ws_size,
                              hipStream_t stream) {
  const float* x   = (const float*)d_in[0];
  const int* ei    = (const int*)d_in[1];
  const float* W1  = (const float*)d_in[2];
  const float* b1  = (const float*)d_in[3];
  const float* W2  = (const float*)d_in[4];
  const float* b2  = (const float*)d_in[5];
  const float* Wm1 = (const float*)d_in[6];
  const float* bm1 = (const float*)d_in[7];
  const float* Wm2 = (const float*)d_in[8];
  const float* bm2 = (const float*)d_in[9];
  float* out = (float*)d_out;

  const int* src = ei;
  const int* dst = ei + NE;

  // workspace layout (high-water 92,708,864 B; round-1 proved ws_size >= 102.8 MB)
  char* ws = (char*)d_ws;
  int*   deg    = (int*)(ws + 0x000000);
  int*   rs     = (int*)(ws + 0x080000);
  int*   cursor = (int*)(ws + 0x100000);
  float* dinv   = (float*)(ws + 0x180000);
  int*   bsum   = (int*)(ws + 0x200000);
  int*   boff   = (int*)(ws + 0x210000);
  unsigned short* Bp = (unsigned short*)(ws + 0x220000);     // 128 KB
  uint2* sde    = (uint2*)(ws + 0x240000);                   // 12.8 MB
  unsigned short* bufT = (unsigned short*)(ws + 0xE80000);   // 25.6 MB: T1' then h2
  unsigned short* hbuf = (unsigned short*)(ws + 0x2700000);  // 25.6 MB: T2' then u
  unsigned short* vbuf = (unsigned short*)(ws + 0x4000000);  // 25.6 MB: v

  const int gN = NB;
  const int gPart = (NE / 256) * 8;    // 50000
  const int gRow = (NN + 63) / 64;     // 1563
  const int gDual = (NN + 127) / 128;  // 782
  const int gAgg = (NN + 3) / 4;       // 25000
  const int gEdge = 800 * 8;           // 6400: 800 blocks x 4 waves per class >= max batches/class

  // CSR build + weight prep
  k_init<<<gN, 256, 0, stream>>>(deg, W1, W2, Wm1, Bp);
  k_hist<<<gPart, 256, 0, stream>>>(dst, deg);
  k_scan1<<<gN, 256, 0, stream>>>(deg, cursor, bsum);
  k_scan2<<<1, 64, 0, stream>>>(bsum, boff);
  k_scan3<<<gN, 256, 0, stream>>>(deg, cursor, boff, rs, dinv);
  k_fill<<<gPart, 256, 0, stream>>>(src, dst, cursor, sde);

  // layer 1 GEMM: T1' = dinv*(x@W1) -> bufT
  k_gemm_mfma_f32<<<gRow, 256, 0, stream>>>(x, Bp, bufT, dinv, NN);

  // FUSED layer-1 agg + layer-2 GEMM: T2' = dinv*(relu(agg(T1')+b1) @ W2) -> hbuf
  k_aggemm<<<gRow, 512, 0, stream>>>(bufT, rs, sde, dinv, b1, Bp + 16384, hbuf);

  // layer-2 agg: h2 = relu(dinv*(T2'[d]+sum)+b2) -> bufT
  k_agg<<<gAgg, 256, 0, stream>>>(hbuf, rs, sde, dinv, b2, bufT);

  // u = h2 @ Wm1_top -> hbuf, v = h2 @ Wm1_bot -> vbuf
  k_gemm_dual<<<gDual, 512, 0, stream>>>(bufT, Bp + 2 * 16384, hbuf, vbuf, NN);

  // edge epilogue (XCD-pinned)
  k_edge<<<gEdge, 256, 0, stream>>>(hbuf, vbuf, sde, rs, bm1, Wm2, bm2, out);
}

// Round 12
// 406.411 us; speedup vs baseline: 1.0342x; 1.0342x over previous
//
#include <hip/hip_runtime.h>
#include <math.h>

#define NN 100000
#define NE 1600000
#define NB 391     // ceil(NN/256)
#define PART 12500 // NN/8 nodes per XCD partition

typedef __attribute__((ext_vector_type(8))) short bf16x8;
typedef __attribute__((ext_vector_type(4))) float f32x4;

__device__ inline unsigned short f2bf(float f) {
  unsigned int u = __float_as_uint(f);
  u = u + 0x7fffu + ((u >> 16) & 1u);
  return (unsigned short)(u >> 16);
}
// packed dword (2 bf16) -> 2 floats
__device__ inline void unpk(unsigned int w, float& a, float& b) {
  a = __uint_as_float(w << 16);
  b = __uint_as_float(w & 0xffff0000u);
}

// ---------------- init: zero deg + weight prep (merged) ----------------
__global__ __launch_bounds__(256) void k_init(int* __restrict__ deg,
                                              const float* __restrict__ W1, const float* __restrict__ W2,
                                              const float* __restrict__ Wm1, unsigned short* __restrict__ Bp) {
  int gid = blockIdx.x * 256 + threadIdx.x;
  if (gid < NN) deg[gid] = 0;
  if (gid < 65536) {
    int idx = gid & 16383;
    int m = gid >> 14;
    int u = idx & 7;
    int lane = (idx >> 3) & 63;
    int ft = idx >> 9;
    int t = ft & 3, f = ft >> 2;
    int n = f * 16 + (lane & 15);
    int k = t * 32 + (lane >> 4) * 8 + u;
    const float* Wsrc = (m == 0) ? W1 : (m == 1) ? W2 : Wm1;
    int krow = (m == 3) ? (k + 128) : k;
    Bp[gid] = f2bf(Wsrc[(size_t)krow * 128 + n]);
  }
}

// XCD-partitioned histogram
__global__ __launch_bounds__(256) void k_hist(const int* __restrict__ dst, int* __restrict__ deg) {
  int b = blockIdx.x;
  int xcd = b & 7;
  int e = (b >> 3) * 256 + threadIdx.x;
  int d = dst[e];
  if ((unsigned)(d - xcd * PART) < (unsigned)PART) atomicAdd(&deg[d], 1);
}

__global__ __launch_bounds__(256) void k_scan1(const int* __restrict__ deg, int* __restrict__ tmp,
                                               int* __restrict__ bsum) {
  __shared__ int wsum[4];
  int i = blockIdx.x * 256 + threadIdx.x;
  int v = (i < NN) ? deg[i] : 0;
  int x = v;
#pragma unroll
  for (int d = 1; d < 64; d <<= 1) {
    int y = __shfl_up(x, d);
    if ((threadIdx.x & 63) >= d) x += y;
  }
  if ((threadIdx.x & 63) == 63) wsum[threadIdx.x >> 6] = x;
  __syncthreads();
  int add = 0;
  for (int w = 0; w < (threadIdx.x >> 6); ++w) add += wsum[w];
  int incl = x + add;
  if (i < NN) tmp[i] = incl - v;
  if (threadIdx.x == 255) bsum[blockIdx.x] = incl;
}

// merged scan2+scan3: each block reduces bsum[0..b) itself, then finalizes rs/cursor/dinv
__global__ __launch_bounds__(256) void k_scan23(const int* __restrict__ deg, int* __restrict__ cursor,
                                                const int* __restrict__ bsum, int* __restrict__ rs,
                                                float* __restrict__ dinv) {
  __shared__ int part[256];
  int b = blockIdx.x, t = threadIdx.x;
  int s = 0;
  for (int i = t; i < b; i += 256) s += bsum[i];
  part[t] = s;
  __syncthreads();
#pragma unroll
  for (int off = 128; off > 0; off >>= 1) {
    if (t < off) part[t] += part[t + off];
    __syncthreads();
  }
  int base = part[0];
  int i = b * 256 + t;
  if (i < NN) {
    int v = cursor[i] + base;  // cursor held within-block exclusive from scan1
    rs[i] = v;
    cursor[i] = v;  // atomic cursor for k_fill
    dinv[i] = rsqrtf((float)(deg[i] + 1));
  }
  if (i == 0) rs[NN] = NE;
}

// XCD-partitioned fill. packed: lo = src | (d<<17) ; hi = (d>>15) | (eid<<2)
__global__ __launch_bounds__(256) void k_fill(const int* __restrict__ src, const int* __restrict__ dst,
                                              int* __restrict__ cursor, uint2* __restrict__ sde) {
  int b = blockIdx.x;
  int xcd = b & 7;
  int e = (b >> 3) * 256 + threadIdx.x;
  int d = dst[e];
  int s = src[e];
  if ((unsigned)(d - xcd * PART) < (unsigned)PART) {
    int p = atomicAdd(&cursor[d], 1);
    unsigned int lo = (unsigned int)s | ((unsigned int)d << 17);
    unsigned int hi = ((unsigned int)d >> 15) | ((unsigned int)e << 2);
    sde[p] = make_uint2(lo, hi);
  }
}

// ---------------- MFMA GEMM, fp32 A (layer 1: T1' = dinv * (x @ W1)) ----------------
__global__ __launch_bounds__(256) void k_gemm_mfma_f32(const float* __restrict__ A,
                                                       const unsigned short* __restrict__ Bp,
                                                       unsigned short* __restrict__ Y,
                                                       const float* __restrict__ scale, int nrows) {
  __shared__ unsigned short BL[16384];
  {
    const uint4* gp = (const uint4*)Bp;
    uint4* sp = (uint4*)BL;
#pragma unroll
    for (int i = 0; i < 8; ++i) sp[threadIdx.x + i * 256] = gp[threadIdx.x + i * 256];
  }
  __syncthreads();

  const int w = threadIdx.x >> 6, lane = threadIdx.x & 63;
  const int r = lane & 15, g = lane >> 4;
  const int rowbase = blockIdx.x * 64 + w * 16;
  const int arow = rowbase + r;

  bf16x8 av[4];
  if (arow < nrows) {
#pragma unroll
    for (int t = 0; t < 4; ++t) {
      float4 a0 = *(const float4*)(A + (size_t)arow * 128 + g * 8 + t * 32);
      float4 a1 = *(const float4*)(A + (size_t)arow * 128 + g * 8 + t * 32 + 4);
      bf16x8 pk;
      pk[0] = (short)f2bf(a0.x); pk[1] = (short)f2bf(a0.y);
      pk[2] = (short)f2bf(a0.z); pk[3] = (short)f2bf(a0.w);
      pk[4] = (short)f2bf(a1.x); pk[5] = (short)f2bf(a1.y);
      pk[6] = (short)f2bf(a1.z); pk[7] = (short)f2bf(a1.w);
      av[t] = pk;
    }
  } else {
#pragma unroll
    for (int t = 0; t < 4; ++t) av[t] = (bf16x8){0, 0, 0, 0, 0, 0, 0, 0};
  }

  f32x4 acc[8];
#pragma unroll
  for (int f = 0; f < 8; ++f) acc[f] = (f32x4){0.f, 0.f, 0.f, 0.f};

#pragma unroll
  for (int f = 0; f < 8; ++f)
#pragma unroll
    for (int t = 0; t < 4; ++t) {
      bf16x8 bv = *(const bf16x8*)(&BL[(((f << 2) | t) << 9) | (lane << 3)]);
      acc[f] = __builtin_amdgcn_mfma_f32_16x16x32_bf16(av[t], bv, acc[f], 0, 0, 0);
    }

#pragma unroll
  for (int j = 0; j < 4; ++j) {
    int row = rowbase + g * 4 + j;
    if (row < nrows) {
      float sc = scale[row];
#pragma unroll
      for (int f = 0; f < 8; ++f) Y[(size_t)row * 128 + f * 16 + r] = f2bf(acc[f][j] * sc);
    }
  }
}

// ---------------- MFMA GEMM, bf16 A (layer 2: T2' = dinv * (h1 @ W2)) ----------------
__global__ __launch_bounds__(256) void k_gemm_mfma(const unsigned short* __restrict__ A,
                                                   const unsigned short* __restrict__ Bp,
                                                   unsigned short* __restrict__ Y,
                                                   const float* __restrict__ scale, int nrows) {
  __shared__ unsigned short BL[16384];
  {
    const uint4* gp = (const uint4*)Bp;
    uint4* sp = (uint4*)BL;
#pragma unroll
    for (int i = 0; i < 8; ++i) sp[threadIdx.x + i * 256] = gp[threadIdx.x + i * 256];
  }
  __syncthreads();

  const int w = threadIdx.x >> 6, lane = threadIdx.x & 63;
  const int r = lane & 15, g = lane >> 4;
  const int rowbase = blockIdx.x * 64 + w * 16;
  const int arow = rowbase + r;

  bf16x8 av[4];
  if (arow < nrows) {
#pragma unroll
    for (int t = 0; t < 4; ++t) av[t] = *(const bf16x8*)(A + (size_t)arow * 128 + g * 8 + t * 32);
  } else {
#pragma unroll
    for (int t = 0; t < 4; ++t) av[t] = (bf16x8){0, 0, 0, 0, 0, 0, 0, 0};
  }

  f32x4 acc[8];
#pragma unroll
  for (int f = 0; f < 8; ++f) acc[f] = (f32x4){0.f, 0.f, 0.f, 0.f};

#pragma unroll
  for (int f = 0; f < 8; ++f)
#pragma unroll
    for (int t = 0; t < 4; ++t) {
      bf16x8 bv = *(const bf16x8*)(&BL[(((f << 2) | t) << 9) | (lane << 3)]);
      acc[f] = __builtin_amdgcn_mfma_f32_16x16x32_bf16(av[t], bv, acc[f], 0, 0, 0);
    }

#pragma unroll
  for (int j = 0; j < 4; ++j) {
    int row = rowbase + g * 4 + j;
    if (row < nrows) {
      float sc = scale[row];
#pragma unroll
      for (int f = 0; f < 8; ++f) Y[(size_t)row * 128 + f * 16 + r] = f2bf(acc[f][j] * sc);
    }
  }
}

// ---------------- dual MFMA GEMM: U = A@Wm1t, V = A@Wm1b ----------------
__global__ __launch_bounds__(512) void k_gemm_dual(const unsigned short* __restrict__ A,
                                                   const unsigned short* __restrict__ Bp2,
                                                   unsigned short* __restrict__ U,
                                                   unsigned short* __restrict__ V, int nrows) {
  __shared__ unsigned short BL[32768];
  {
    const uint4* gp = (const uint4*)Bp2;
    uint4* sp = (uint4*)BL;
#pragma unroll
    for (int i = 0; i < 8; ++i) sp[threadIdx.x + i * 512] = gp[threadIdx.x + i * 512];
  }
  __syncthreads();

  const int w = threadIdx.x >> 6, lane = threadIdx.x & 63;
  const int r = lane & 15, g = lane >> 4;
  const int rowbase = blockIdx.x * 128 + w * 16;
  const int arow = rowbase + r;

  bf16x8 av[4];
  if (arow < nrows) {
#pragma unroll
    for (int t = 0; t < 4; ++t) av[t] = *(const bf16x8*)(A + (size_t)arow * 128 + g * 8 + t * 32);
  } else {
#pragma unroll
    for (int t = 0; t < 4; ++t) av[t] = (bf16x8){0, 0, 0, 0, 0, 0, 0, 0};
  }

  f32x4 accU[8], accV[8];
#pragma unroll
  for (int f = 0; f < 8; ++f) {
    accU[f] = (f32x4){0.f, 0.f, 0.f, 0.f};
    accV[f] = (f32x4){0.f, 0.f, 0.f, 0.f};
  }

#pragma unroll
  for (int f = 0; f < 8; ++f)
#pragma unroll
    for (int t = 0; t < 4; ++t) {
      bf16x8 bu = *(const bf16x8*)(&BL[(((f << 2) | t) << 9) | (lane << 3)]);
      bf16x8 bv = *(const bf16x8*)(&BL[16384 + ((((f << 2) | t) << 9) | (lane << 3))]);
      accU[f] = __builtin_amdgcn_mfma_f32_16x16x32_bf16(av[t], bu, accU[f], 0, 0, 0);
      accV[f] = __builtin_amdgcn_mfma_f32_16x16x32_bf16(av[t], bv, accV[f], 0, 0, 0);
    }

#pragma unroll
  for (int j = 0; j < 4; ++j) {
    int row = rowbase + g * 4 + j;
    if (row < nrows) {
#pragma unroll
      for (int f = 0; f < 8; ++f) {
        U[(size_t)row * 128 + f * 16 + r] = f2bf(accU[f][j]);
        V[(size_t)row * 128 + f * 16 + r] = f2bf(accV[f][j]);
      }
    }
  }
}

// ---------------- aggregate, quarter-wave gather ----------------
// out[d] = relu(dinv[d]*(T'[d] + sum_s T'[s]) + b), bf16 out
__global__ __launch_bounds__(256) void k_agg(const unsigned short* __restrict__ T,
                                             const int* __restrict__ rs, const uint2* __restrict__ sde,
                                             const float* __restrict__ dinv, const float* __restrict__ bias,
                                             unsigned short* __restrict__ outB) {
  int node = blockIdx.x * 4 + (threadIdx.x >> 6);
  if (node >= NN) return;
  int lane = threadIdx.x & 63;
  int q = lane >> 4, r = lane & 15;
  int beg = rs[node], end = rs[node + 1];
  float dn = dinv[node];

  float acc[8];
#pragma unroll
  for (int i = 0; i < 8; ++i) acc[i] = 0.f;

  for (int j0 = beg; j0 < end; j0 += 64) {
    int sl = (j0 + lane < end) ? (int)(sde[j0 + lane].x & 0x1FFFFu) : 0;
    int n = end - j0;
    if (n > 64) n = 64;
#pragma unroll 4
    for (int c = 0; c * 4 < n; ++c) {
      int idx = (c << 2) | q;
      int s = __shfl(sl, idx);
      if (idx < n) {
        uint4 hv = *(const uint4*)(T + (size_t)s * 128 + r * 8);
        float f0, f1, f2, f3, f4, f5, f6, f7;
        unpk(hv.x, f0, f1); unpk(hv.y, f2, f3);
        unpk(hv.z, f4, f5); unpk(hv.w, f6, f7);
        acc[0] += f0; acc[1] += f1; acc[2] += f2; acc[3] += f3;
        acc[4] += f4; acc[5] += f5; acc[6] += f6; acc[7] += f7;
      }
    }
  }

#pragma unroll
  for (int i = 0; i < 8; ++i) {
    acc[i] += __shfl_xor(acc[i], 16);
    acc[i] += __shfl_xor(acc[i], 32);
  }

  uint4 sv = *(const uint4*)(T + (size_t)node * 128 + r * 8);
  float s0, s1, s2, s3, s4, s5, s6, s7;
  unpk(sv.x, s0, s1); unpk(sv.y, s2, s3);
  unpk(sv.z, s4, s5); unpk(sv.w, s6, s7);
  float4 ba = *(const float4*)(bias + r * 8);
  float4 bb = *(const float4*)(bias + r * 8 + 4);
  float o0 = fmaxf(fmaf(dn, acc[0] + s0, ba.x), 0.f);
  float o1 = fmaxf(fmaf(dn, acc[1] + s1, ba.y), 0.f);
  float o2 = fmaxf(fmaf(dn, acc[2] + s2, ba.z), 0.f);
  float o3 = fmaxf(fmaf(dn, acc[3] + s3, ba.w), 0.f);
  float o4 = fmaxf(fmaf(dn, acc[4] + s4, bb.x), 0.f);
  float o5 = fmaxf(fmaf(dn, acc[5] + s5, bb.y), 0.f);
  float o6 = fmaxf(fmaf(dn, acc[6] + s6, bb.z), 0.f);
  float o7 = fmaxf(fmaf(dn, acc[7] + s7, bb.w), 0.f);
  if (q == 0) {
    uint4 pv;
    pv.x = (unsigned int)f2bf(o0) | ((unsigned int)f2bf(o1) << 16);
    pv.y = (unsigned int)f2bf(o2) | ((unsigned int)f2bf(o3) << 16);
    pv.z = (unsigned int)f2bf(o4) | ((unsigned int)f2bf(o5) << 16);
    pv.w = (unsigned int)f2bf(o6) | ((unsigned int)f2bf(o7) << 16);
    *(uint4*)(outB + (size_t)node * 128 + r * 8) = pv;
  }
}

// ---------------- edge epilogue, XCD-pinned quarter-wave gather + LDS reduce ----------------
__global__ __launch_bounds__(256) void k_edge(const unsigned short* __restrict__ u,
                                              const unsigned short* __restrict__ v,
                                              const uint2* __restrict__ sde, const int* __restrict__ rs,
                                              const float* __restrict__ bm1, const float* __restrict__ Wm2,
                                              const float* __restrict__ bm2, float* __restrict__ out) {
  __shared__ float red[4][16 * 65];
  const int w = threadIdx.x >> 6;
  const int lane = threadIdx.x & 63;
  const int q = lane >> 4, r = lane & 15;
  float* __restrict__ myred = &red[w][0];

  const int cls = blockIdx.x & 7;
  const int bi = blockIdx.x >> 3;  // 0..799
  const int lo = rs[cls * PART] >> 6;
  const int hi = (rs[(cls + 1) * PART] + 63) >> 6;
  const int bat = lo + bi * 4 + w;
  const bool active = bat < hi;

  float bmv[8], w2[8];
  {
    float4 a = *(const float4*)(bm1 + r * 8);
    float4 b = *(const float4*)(bm1 + r * 8 + 4);
    bmv[0] = a.x; bmv[1] = a.y; bmv[2] = a.z; bmv[3] = a.w;
    bmv[4] = b.x; bmv[5] = b.y; bmv[6] = b.z; bmv[7] = b.w;
    float4 c = *(const float4*)(Wm2 + r * 8);
    float4 d = *(const float4*)(Wm2 + r * 8 + 4);
    w2[0] = c.x; w2[1] = c.y; w2[2] = c.z; w2[3] = c.w;
    w2[4] = d.x; w2[5] = d.y; w2[6] = d.z; w2[7] = d.w;
  }
  const float b2 = bm2[0];

  uint2 ev = make_uint2(0u, 0u);
  if (active) ev = sde[bat * 64 + lane];
  const int sl = (int)(ev.x & 0x1FFFFu);
  const int dl = (int)((ev.x >> 17) | ((ev.y & 3u) << 15));

  if (active) {
    int cur = -1;
    float vb[8];
#pragma unroll
    for (int i = 0; i < 8; ++i) vb[i] = 0.f;

#pragma unroll 4
    for (int c = 0; c < 16; ++c) {
      int idx = (c << 2) | q;
      int s = __shfl(sl, idx);
      int d = __shfl(dl, idx);
      uint4 uu = *(const uint4*)(u + (size_t)s * 128 + r * 8);
      if (d != cur) {
        uint4 vv = *(const uint4*)(v + (size_t)d * 128 + r * 8);
        float g0, g1, g2, g3, g4, g5, g6, g7;
        unpk(vv.x, g0, g1); unpk(vv.y, g2, g3);
        unpk(vv.z, g4, g5); unpk(vv.w, g6, g7);
        vb[0] = g0 + bmv[0]; vb[1] = g1 + bmv[1];
        vb[2] = g2 + bmv[2]; vb[3] = g3 + bmv[3];
        vb[4] = g4 + bmv[4]; vb[5] = g5 + bmv[5];
        vb[6] = g6 + bmv[6]; vb[7] = g7 + bmv[7];
        cur = d;
      }
      float f0, f1, f2, f3, f4, f5, f6, f7;
      unpk(uu.x, f0, f1); unpk(uu.y, f2, f3);
      unpk(uu.z, f4, f5); unpk(uu.w, f6, f7);
      float p = 0.f;
      p = fmaf(fmaxf(f0 + vb[0], 0.f), w2[0], p);
      p = fmaf(fmaxf(f1 + vb[1], 0.f), w2[1], p);
      p = fmaf(fmaxf(f2 + vb[2], 0.f), w2[2], p);
      p = fmaf(fmaxf(f3 + vb[3], 0.f), w2[3], p);
      p = fmaf(fmaxf(f4 + vb[4], 0.f), w2[4], p);
      p = fmaf(fmaxf(f5 + vb[5], 0.f), w2[5], p);
      p = fmaf(fmaxf(f6 + vb[6], 0.f), w2[6], p);
      p = fmaf(fmaxf(f7 + vb[7], 0.f), w2[7], p);
      myred[c * 65 + q * 16 + r] = p;
    }
  }
  __syncthreads();

  if (active) {
    const float* row = &myred[(lane >> 2) * 65 + (lane & 3) * 16];
    float s0 = 0.f, s1 = 0.f;
#pragma unroll
    for (int k = 0; k < 16; k += 2) {
      s0 += row[k];
      s1 += row[k + 1];
    }
    float logit = s0 + s1 + b2;
    int eid = (int)(ev.y >> 2);
    out[eid] = 1.f / (1.f + __expf(-logit));
  }
}

// ---------------- launch ----------------
extern "C" void kernel_launch(void* const* d_in, const int* in_sizes, int n_in,
                              void* d_out, int out_size, void* d_ws, size_t ws_size,
                              hipStream_t stream) {
  const float* x   = (const float*)d_in[0];
  const int* ei    = (const int*)d_in[1];
  const float* W1  = (const float*)d_in[2];
  const float* b1  = (const float*)d_in[3];
  const float* W2  = (const float*)d_in[4];
  const float* b2  = (const float*)d_in[5];
  const float* Wm1 = (const float*)d_in[6];
  const float* bm1 = (const float*)d_in[7];
  const float* Wm2 = (const float*)d_in[8];
  const float* bm2 = (const float*)d_in[9];
  float* out = (float*)d_out;

  const int* src = ei;
  const int* dst = ei + NE;

  // workspace layout (high-water 92,708,864 B; round-1 proved ws_size >= 102.8 MB)
  char* ws = (char*)d_ws;
  int*   deg    = (int*)(ws + 0x000000);
  int*   rs     = (int*)(ws + 0x080000);
  int*   cursor = (int*)(ws + 0x100000);
  float* dinv   = (float*)(ws + 0x180000);
  int*   bsum   = (int*)(ws + 0x200000);
  unsigned short* Bp = (unsigned short*)(ws + 0x220000);     // 128 KB
  uint2* sde    = (uint2*)(ws + 0x240000);                   // 12.8 MB
  unsigned short* bufT = (unsigned short*)(ws + 0xE80000);   // 25.6 MB: T1' / T2' / u
  unsigned short* hbuf = (unsigned short*)(ws + 0x2700000);  // 25.6 MB: h1 / h2
  unsigned short* vbuf = (unsigned short*)(ws + 0x4000000);  // 25.6 MB: v

  const int gN = NB;
  const int gPart = (NE / 256) * 8;    // 50000
  const int gRow = (NN + 63) / 64;     // 1563
  const int gDual = (NN + 127) / 128;  // 782
  const int gAgg = (NN + 3) / 4;       // 25000
  const int gEdge = 800 * 8;           // 6400

  // CSR build + weight prep (9 launches total)
  k_init<<<gN, 256, 0, stream>>>(deg, W1, W2, Wm1, Bp);
  k_hist<<<gPart, 256, 0, stream>>>(dst, deg);
  k_scan1<<<gN, 256, 0, stream>>>(deg, cursor, bsum);
  k_scan23<<<gN, 256, 0, stream>>>(deg, cursor, bsum, rs, dinv);
  k_fill<<<gPart, 256, 0, stream>>>(src, dst, cursor, sde);

  // layer 1: T1' = dinv*(x@W1) -> bufT; h1 = agg -> hbuf
  k_gemm_mfma_f32<<<gRow, 256, 0, stream>>>(x, Bp, bufT, dinv, NN);
  k_agg<<<gAgg, 256, 0, stream>>>(bufT, rs, sde, dinv, b1, hbuf);

  // layer 2: T2' = dinv*(h1@W2) -> bufT; h2 = agg -> hbuf
  k_gemm_mfma<<<gRow, 256, 0, stream>>>(hbuf, Bp + 16384, bufT, dinv, NN);
  k_agg<<<gAgg, 256, 0, stream>>>(bufT, rs, sde, dinv, b2, hbuf);

  // u = h2 @ Wm1_top -> bufT, v = h2 @ Wm1_bot -> vbuf
  k_gemm_dual<<<gDual, 512, 0, stream>>>(hbuf, Bp + 2 * 16384, bufT, vbuf, NN);

  // edge epilogue (XCD-pinned)
  k_edge<<<gEdge, 256, 0, stream>>>(bufT, vbuf, sde, rs, bm1, Wm2, bm2, out);
}